// Round 1
// baseline (269.262 us; speedup 1.0000x reference)
//
#include <hip/hip_runtime.h>
#include <math.h>

#define T_LEN   720
#define V_DIM   64
#define KB      4      // number of edited bins
#define NKNOTS  4
#define BLOCK   768
#define TSLICE  15     // 720 / 48 slices
#define WAVES   12     // 768 / 64

// out[b,t,v] = (y[b,t,v] + (2/T) * sum_k (ReC[v,k]*cos(2pi*k_b*t/T) - ImC[v,k]*sin(...))) * env[t,v]
// C[v,k] = F_k[b,v] * (scale[v,k] - 1),  scale = (1+a)*exp(i*tanh(phi)*0.25)

__global__ __launch_bounds__(BLOCK) void SeasonalEnvelopeAdapter_kernel(
    const float* __restrict__ y,
    const float* __restrict__ a,
    const float* __restrict__ phi,
    const float* __restrict__ env_knots,
    const int*   __restrict__ k_bins,
    float* __restrict__ out)
{
    __shared__ __align__(16) float tab[T_LEN * 8];     // [t][k][{cos,sin}]
    __shared__ float red[WAVES][16][32];
    __shared__ float sums[16][32];
    __shared__ float coef[V_DIM][8];                   // [v][0..3]=Re*2/T, [v][4..7]=Im*2/T
    __shared__ float kn[V_DIM][NKNOTS];

    const int tid  = threadIdx.x;
    const int b    = blockIdx.x;
    const int g    = tid & 15;      // float4 group -> v0 = 4*g
    const int s    = tid >> 4;      // t-slice 0..47
    const int lane = tid & 63;
    const int w    = tid >> 6;      // wave 0..11

    // ---- Phase 0: trig table (angle reduced mod T in ints -> small args) + knots ----
    for (int e = tid; e < T_LEN * KB; e += BLOCK) {
        int t = e >> 2, k = e & 3;
        int kb = k_bins[k];
        int m  = (kb * t) % T_LEN;
        float th = (float)m * (6.28318530717958647692f / (float)T_LEN);
        float sn, cs;
        sincosf(th, &sn, &cs);
        tab[t * 8 + k * 2 + 0] = cs;
        tab[t * 8 + k * 2 + 1] = sn;
    }
    if (tid < V_DIM * NKNOTS) {
        int v = tid >> 2, n = tid & 3;
        float kv = env_knots[v * NKNOTS + n];
        kn[v][n] = fminf(fmaxf(kv, 0.5f), 1.5f);
    }
    __syncthreads();

    // ---- Phase 1: load y slice into registers, accumulate DFT partials ----
    const size_t base = ((size_t)b * T_LEN) * V_DIM + (size_t)(g << 2);
    float4 yv[TSLICE];
    float accre[4][4], accim[4][4];
    #pragma unroll
    for (int j = 0; j < 4; ++j)
        #pragma unroll
        for (int k = 0; k < 4; ++k) { accre[j][k] = 0.f; accim[j][k] = 0.f; }

    #pragma unroll
    for (int i = 0; i < TSLICE; ++i) {
        int t = s * TSLICE + i;
        yv[i] = *(const float4*)(y + base + (size_t)t * V_DIM);
    }
    #pragma unroll
    for (int i = 0; i < TSLICE; ++i) {
        int t = s * TSLICE + i;
        float4 f0 = *(const float4*)(&tab[t * 8]);
        float4 f1 = *(const float4*)(&tab[t * 8 + 4]);
        const float cs[4] = {f0.x, f0.z, f1.x, f1.z};
        const float sn[4] = {f0.y, f0.w, f1.y, f1.w};
        const float yj[4] = {yv[i].x, yv[i].y, yv[i].z, yv[i].w};
        #pragma unroll
        for (int j = 0; j < 4; ++j)
            #pragma unroll
            for (int k = 0; k < 4; ++k) {
                accre[j][k] = fmaf(yj[j], cs[k], accre[j][k]);
                accim[j][k] = fmaf(yj[j], sn[k], accim[j][k]);
            }
    }

    // ---- Reduce: 4 slices within wave via shuffle, then 12 waves via LDS ----
    #pragma unroll
    for (int j = 0; j < 4; ++j)
        #pragma unroll
        for (int k = 0; k < 4; ++k) {
            float r = accre[j][k], im = accim[j][k];
            r  += __shfl_xor(r, 16, 64);  r  += __shfl_xor(r, 32, 64);
            im += __shfl_xor(im, 16, 64); im += __shfl_xor(im, 32, 64);
            accre[j][k] = r; accim[j][k] = im;
        }
    if (lane < 16) {
        #pragma unroll
        for (int j = 0; j < 4; ++j)
            #pragma unroll
            for (int k = 0; k < 4; ++k) {
                red[w][lane][j * 8 + k]     = accre[j][k];
                red[w][lane][j * 8 + 4 + k] = accim[j][k];
            }
    }
    __syncthreads();
    if (tid < 512) {
        int g2 = tid >> 5, c = tid & 31;
        float sum = 0.f;
        #pragma unroll
        for (int ww = 0; ww < WAVES; ++ww) sum += red[ww][g2][c];
        sums[g2][c] = sum;
    }
    __syncthreads();
    // ---- Apply (scale-1) transform: C = (cr - i*ci) * ((sr-1) + i*si) ----
    if (tid < 256) {
        int v = tid >> 2, k = tid & 3;
        int j = v & 3, g2 = v >> 2;
        float cr = sums[g2][j * 8 + k];
        float ci = sums[g2][j * 8 + 4 + k];
        float amp = 1.0f + a[v * KB + k];
        float ph  = tanhf(phi[v * KB + k]) * 0.25f;
        float sph, cph;
        sincosf(ph, &sph, &cph);
        float sr = amp * cph - 1.0f;   // Re(scale) - 1
        float si = amp * sph;          // Im(scale)
        const float sc = 2.0f / (float)T_LEN;
        coef[v][k]     = (cr * sr + ci * si) * sc;   // Re C * 2/T
        coef[v][4 + k] = (cr * si - ci * sr) * sc;   // Im C * 2/T
    }
    __syncthreads();

    // ---- Phase 2: reconstruct + envelope, store ----
    float cre[4][4], cim[4][4], knr[4][4];
    #pragma unroll
    for (int j = 0; j < 4; ++j) {
        int v = (g << 2) + j;
        #pragma unroll
        for (int k = 0; k < 4; ++k) {
            cre[j][k] = coef[v][k];
            cim[j][k] = coef[v][4 + k];
        }
        #pragma unroll
        for (int n = 0; n < 4; ++n) knr[j][n] = kn[v][n];
    }

    const float posScale = 3.0f / 719.0f;
    #pragma unroll
    for (int i = 0; i < TSLICE; ++i) {
        int t = s * TSLICE + i;
        float4 f0 = *(const float4*)(&tab[t * 8]);
        float4 f1 = *(const float4*)(&tab[t * 8 + 4]);
        const float cs[4] = {f0.x, f0.z, f1.x, f1.z};
        const float sn[4] = {f0.y, f0.w, f1.y, f1.w};
        float pos = (float)t * posScale;
        int idx = (int)pos; idx = idx > 2 ? 2 : idx;
        float frac = pos - (float)idx;
        const float yj[4] = {yv[i].x, yv[i].y, yv[i].z, yv[i].w};
        float oj[4];
        #pragma unroll
        for (int j = 0; j < 4; ++j) {
            float d = 0.f;
            #pragma unroll
            for (int k = 0; k < 4; ++k)
                d = fmaf(cre[j][k], cs[k], fmaf(-cim[j][k], sn[k], d));
            float e0 = (idx == 0) ? knr[j][0] : ((idx == 1) ? knr[j][1] : knr[j][2]);
            float e1 = (idx == 0) ? knr[j][1] : ((idx == 1) ? knr[j][2] : knr[j][3]);
            float env = fmaf(e1 - e0, frac, e0);
            oj[j] = (yj[j] + d) * env;
        }
        float4 o; o.x = oj[0]; o.y = oj[1]; o.z = oj[2]; o.w = oj[3];
        *(float4*)(out + base + (size_t)t * V_DIM) = o;
    }
}

extern "C" void kernel_launch(void* const* d_in, const int* in_sizes, int n_in,
                              void* d_out, int out_size, void* d_ws, size_t ws_size,
                              hipStream_t stream) {
    const float* y         = (const float*)d_in[0];
    const float* a         = (const float*)d_in[1];
    const float* phi       = (const float*)d_in[2];
    const float* env_knots = (const float*)d_in[3];
    const int*   k_bins    = (const int*)d_in[4];
    float* out = (float*)d_out;

    int B = in_sizes[0] / (T_LEN * V_DIM);
    SeasonalEnvelopeAdapter_kernel<<<B, BLOCK, 0, stream>>>(y, a, phi, env_knots, k_bins, out);
}

// Round 2
// 220.601 us; speedup vs baseline: 1.2206x; 1.2206x over previous
//
#include <hip/hip_runtime.h>
#include <math.h>

#define T_LEN   720
#define V_DIM   64
#define KB      4      // number of edited bins
#define NKNOTS  4
#define BLOCK   768
#define TSLICE  15     // 720 / 48 slices
#define WAVES   12     // 768 / 64

// out[b,t,v] = (y[b,t,v] + (2/T) * sum_k (ReC[v,k]*cos(2pi*k_b*t/T) - ImC[v,k]*sin(...))) * env[t,v]
// C[v,k] = F_k[b,v] * (scale[v,k] - 1),  scale = (1+a)*exp(i*tanh(phi)*0.25)
//
// Phase 2 RE-READS y from global instead of caching it in registers:
// R1 showed VGPR=84 with ~92+ live regs needed -> spill -> +300MB HBM write.
// The block's 184KB y-slice is L2/L3-resident between the phases.

__global__ __launch_bounds__(BLOCK) void SeasonalEnvelopeAdapter_kernel(
    const float* __restrict__ y,
    const float* __restrict__ a,
    const float* __restrict__ phi,
    const float* __restrict__ env_knots,
    const int*   __restrict__ k_bins,
    float* __restrict__ out)
{
    __shared__ __align__(16) float tab[T_LEN * 8];     // [t][k][{cos,sin}]
    __shared__ float red[16][WAVES][33];               // padded: stride 396 -> <=2-way bank alias
    __shared__ float sums[16][32];
    __shared__ float coef[V_DIM][8];                   // [v][0..3]=Re*2/T, [v][4..7]=Im*2/T
    __shared__ float kn[V_DIM][NKNOTS];

    const int tid  = threadIdx.x;
    const int b    = blockIdx.x;
    const int g    = tid & 15;      // float4 group -> v0 = 4*g
    const int s    = tid >> 4;      // t-slice 0..47
    const int lane = tid & 63;
    const int w    = tid >> 6;      // wave 0..11

    // ---- Phase 0: trig table (angle reduced mod T in ints -> small args) + knots ----
    for (int e = tid; e < T_LEN * KB; e += BLOCK) {
        int t = e >> 2, k = e & 3;
        int kb = k_bins[k];
        int m  = (kb * t) % T_LEN;
        float th = (float)m * (6.28318530717958647692f / (float)T_LEN);
        float sn, cs;
        sincosf(th, &sn, &cs);
        tab[t * 8 + k * 2 + 0] = cs;
        tab[t * 8 + k * 2 + 1] = sn;
    }
    if (tid < V_DIM * NKNOTS) {
        int v = tid >> 2, n = tid & 3;
        float kv = env_knots[v * NKNOTS + n];
        kn[v][n] = fminf(fmaxf(kv, 0.5f), 1.5f);
    }
    __syncthreads();

    // ---- Phase 1: stream y, accumulate DFT partials (no register cache) ----
    const size_t base = ((size_t)b * T_LEN) * V_DIM + (size_t)(g << 2);
    float accre[4][4], accim[4][4];
    #pragma unroll
    for (int j = 0; j < 4; ++j)
        #pragma unroll
        for (int k = 0; k < 4; ++k) { accre[j][k] = 0.f; accim[j][k] = 0.f; }

    #pragma unroll
    for (int i = 0; i < TSLICE; ++i) {
        int t = s * TSLICE + i;
        float4 yv = *(const float4*)(y + base + (size_t)t * V_DIM);
        float4 f0 = *(const float4*)(&tab[t * 8]);
        float4 f1 = *(const float4*)(&tab[t * 8 + 4]);
        const float cs[4] = {f0.x, f0.z, f1.x, f1.z};
        const float sn[4] = {f0.y, f0.w, f1.y, f1.w};
        const float yj[4] = {yv.x, yv.y, yv.z, yv.w};
        #pragma unroll
        for (int j = 0; j < 4; ++j)
            #pragma unroll
            for (int k = 0; k < 4; ++k) {
                accre[j][k] = fmaf(yj[j], cs[k], accre[j][k]);
                accim[j][k] = fmaf(yj[j], sn[k], accim[j][k]);
            }
    }

    // ---- Reduce: 4 slices within wave via shuffle, then 12 waves via LDS ----
    #pragma unroll
    for (int j = 0; j < 4; ++j)
        #pragma unroll
        for (int k = 0; k < 4; ++k) {
            float r = accre[j][k], im = accim[j][k];
            r  += __shfl_xor(r, 16, 64);  r  += __shfl_xor(r, 32, 64);
            im += __shfl_xor(im, 16, 64); im += __shfl_xor(im, 32, 64);
            accre[j][k] = r; accim[j][k] = im;
        }
    if (lane < 16) {
        #pragma unroll
        for (int j = 0; j < 4; ++j)
            #pragma unroll
            for (int k = 0; k < 4; ++k) {
                red[lane][w][j * 8 + k]     = accre[j][k];
                red[lane][w][j * 8 + 4 + k] = accim[j][k];
            }
    }
    __syncthreads();
    if (tid < 512) {
        int g2 = tid >> 5, c = tid & 31;
        float sum = 0.f;
        #pragma unroll
        for (int ww = 0; ww < WAVES; ++ww) sum += red[g2][ww][c];
        sums[g2][c] = sum;
    }
    __syncthreads();
    // ---- Apply (scale-1) transform: C = (cr - i*ci) * ((sr-1) + i*si) ----
    if (tid < 256) {
        int v = tid >> 2, k = tid & 3;
        int j = v & 3, g2 = v >> 2;
        float cr = sums[g2][j * 8 + k];
        float ci = sums[g2][j * 8 + 4 + k];
        float amp = 1.0f + a[v * KB + k];
        float ph  = tanhf(phi[v * KB + k]) * 0.25f;
        float sph, cph;
        sincosf(ph, &sph, &cph);
        float sr = amp * cph - 1.0f;   // Re(scale) - 1
        float si = amp * sph;          // Im(scale)
        const float sc = 2.0f / (float)T_LEN;
        coef[v][k]     = (cr * sr + ci * si) * sc;   // Re C * 2/T
        coef[v][4 + k] = (cr * si - ci * sr) * sc;   // Im C * 2/T
    }
    __syncthreads();

    // ---- Phase 2: re-read y (L2/L3-hot), reconstruct + envelope, store ----
    float cre[4][4], cim[4][4], knr[4][4];
    #pragma unroll
    for (int j = 0; j < 4; ++j) {
        int v = (g << 2) + j;
        #pragma unroll
        for (int k = 0; k < 4; ++k) {
            cre[j][k] = coef[v][k];
            cim[j][k] = coef[v][4 + k];
        }
        #pragma unroll
        for (int n = 0; n < 4; ++n) knr[j][n] = kn[v][n];
    }

    const float posScale = 3.0f / 719.0f;
    #pragma unroll
    for (int i = 0; i < TSLICE; ++i) {
        int t = s * TSLICE + i;
        float4 yv = *(const float4*)(y + base + (size_t)t * V_DIM);
        float4 f0 = *(const float4*)(&tab[t * 8]);
        float4 f1 = *(const float4*)(&tab[t * 8 + 4]);
        const float cs[4] = {f0.x, f0.z, f1.x, f1.z};
        const float sn[4] = {f0.y, f0.w, f1.y, f1.w};
        float pos = (float)t * posScale;
        int idx = (int)pos; idx = idx > 2 ? 2 : idx;
        float frac = pos - (float)idx;
        const float yj[4] = {yv.x, yv.y, yv.z, yv.w};
        float oj[4];
        #pragma unroll
        for (int j = 0; j < 4; ++j) {
            float d = 0.f;
            #pragma unroll
            for (int k = 0; k < 4; ++k)
                d = fmaf(cre[j][k], cs[k], fmaf(-cim[j][k], sn[k], d));
            float e0 = (idx == 0) ? knr[j][0] : ((idx == 1) ? knr[j][1] : knr[j][2]);
            float e1 = (idx == 0) ? knr[j][1] : ((idx == 1) ? knr[j][2] : knr[j][3]);
            float env = fmaf(e1 - e0, frac, e0);
            oj[j] = (yj[j] + d) * env;
        }
        float4 o; o.x = oj[0]; o.y = oj[1]; o.z = oj[2]; o.w = oj[3];
        *(float4*)(out + base + (size_t)t * V_DIM) = o;
    }
}

extern "C" void kernel_launch(void* const* d_in, const int* in_sizes, int n_in,
                              void* d_out, int out_size, void* d_ws, size_t ws_size,
                              hipStream_t stream) {
    const float* y         = (const float*)d_in[0];
    const float* a         = (const float*)d_in[1];
    const float* phi       = (const float*)d_in[2];
    const float* env_knots = (const float*)d_in[3];
    const int*   k_bins    = (const int*)d_in[4];
    float* out = (float*)d_out;

    int B = in_sizes[0] / (T_LEN * V_DIM);
    SeasonalEnvelopeAdapter_kernel<<<B, BLOCK, 0, stream>>>(y, a, phi, env_knots, k_bins, out);
}